// Round 7
// baseline (282.647 us; speedup 1.0000x reference)
//
#include <hip/hip_runtime.h>
#include <hip/hip_bf16.h>

// MultiHeadAttention B=2,S=2048,D=1024,H=16,Dh=64. fp32 I/O, bf16 MFMA compute.
// R7 = R6 with gemm_out A-staging bug fixed: each thread now merges/stages BOTH
// A rows (m and m+64) of the 128-row tile (R6 left rows 64..127 stale -> err 39).

typedef short bf16x8 __attribute__((ext_vector_type(8)));
typedef short bf16x4 __attribute__((ext_vector_type(4)));
typedef float f32x4  __attribute__((ext_vector_type(4)));

constexpr size_t NE = (size_t)4096 * 1024;   // elems of [B*S, D]
constexpr size_t NW = (size_t)1024 * 1024;   // elems of [D, D]
constexpr size_t NL = (size_t)4096 * 16;     // l entries per half: (B*S)*H

#if __has_builtin(__builtin_amdgcn_exp2f)
#define EXP2(x) __builtin_amdgcn_exp2f(x)
#else
#define EXP2(x) exp2f(x)
#endif

__device__ __forceinline__ short f2bf(float f) {
  __hip_bfloat16 h = __float2bfloat16(f);
  return *reinterpret_cast<short*>(&h);
}
__device__ __forceinline__ float bf2f(short s) {
  __hip_bfloat16 h = *reinterpret_cast<__hip_bfloat16*>(&s);
  return __bfloat162float(h);
}

__device__ __forceinline__ void cp16(const short* g, short* l) {
  __builtin_amdgcn_global_load_lds(
      (const __attribute__((address_space(1))) void*)g,
      (__attribute__((address_space(3))) void*)l, 16, 0, 0);
}

// swizzled offset into a 64-row x 64-short tile: chunk = 16B unit 0..7
__device__ __forceinline__ int sw(int row, int chunk) {
  return row * 64 + ((chunk ^ (row & 7)) * 8);
}

// ---------------- fused fp32 -> bf16 conversion, 16 slices of 1M elems
__global__ __launch_bounds__(256) void cvt_kernel(
    const float* q, const float* k, const float* v,
    const float* Wq, const float* Wk, const float* Wv, const float* Wo,
    short* qb, short* kb, short* vb,
    short* Wqb, short* Wkb, short* Wvb, short* Wob) {
  const int y = blockIdx.y;
  const float* s; short* d;
  if (y < 12) {
    const int t = y >> 2;
    const size_t off = (size_t)(y & 3) << 20;
    s = (t == 0 ? q : (t == 1 ? k : v)) + off;
    d = (t == 0 ? qb : (t == 1 ? kb : vb)) + off;
  } else {
    s = (y == 12 ? Wq : (y == 13 ? Wk : (y == 14 ? Wv : Wo)));
    d = (y == 12 ? Wqb : (y == 13 ? Wkb : (y == 14 ? Wvb : Wob)));
  }
  size_t i = (size_t)blockIdx.x * 256 + threadIdx.x;
  float4 val = ((const float4*)s)[i];
  bf16x4 o;
  o[0] = f2bf(val.x); o[1] = f2bf(val.y); o[2] = f2bf(val.z); o[3] = f2bf(val.w);
  ((bf16x4*)d)[i] = o;
}

// ---------------- fused Q/K/V projection GEMM: C = (A @ W^T + b) * scale
// 128x128 tile, BK=32, global_load_lds 16B, 4 waves of 64x64.
__global__ __launch_bounds__(256) void gemm_qkv(
    const short* __restrict__ A0, const short* __restrict__ A1, const short* __restrict__ A2,
    const short* __restrict__ W0, const short* __restrict__ W1, const short* __restrict__ W2,
    const float* __restrict__ b0, const float* __restrict__ b1, const float* __restrict__ b2,
    short* __restrict__ C0, short* __restrict__ C1, short* __restrict__ Cv) {
  __shared__ short As[128 * 32];
  __shared__ short Bs[128 * 32];
  const int which = blockIdx.y;
  const short* A    = which == 0 ? A0 : (which == 1 ? A1 : A2);
  const short* W    = which == 0 ? W0 : (which == 1 ? W1 : W2);
  const float* bias = which == 0 ? b0 : (which == 1 ? b1 : b2);
  const float scale = which == 0 ? 0.18033688011112042f : 1.0f;  // 0.125*log2e

  const int tid  = threadIdx.x;
  const int bm   = (int)blockIdx.x >> 3;
  const int bn   = (int)blockIdx.x & 7;
  const int lane = tid & 63, wid = tid >> 6;
  const int g = lane >> 4, l15 = lane & 15;
  const int wm = (wid >> 1) * 64, wn = (wid & 1) * 64;

  const short* Ag = A + (size_t)(bm * 128 + (tid >> 2)) * 1024 + (tid & 3) * 8;
  const short* Wg = W + (size_t)(bn * 128 + (tid >> 2)) * 1024 + (tid & 3) * 8;
  short* AsW = As + wid * 512;
  short* BsW = Bs + wid * 512;

  f32x4 acc[4][4];
#pragma unroll
  for (int i = 0; i < 4; ++i)
#pragma unroll
    for (int j = 0; j < 4; ++j) acc[i][j] = (f32x4){0.f, 0.f, 0.f, 0.f};

  for (int k0 = 0; k0 < 1024; k0 += 32) {
    __syncthreads();
    cp16(Ag + k0,             AsW);
    cp16(Ag + 64 * 1024 + k0, AsW + 2048);
    cp16(Wg + k0,             BsW);
    cp16(Wg + 64 * 1024 + k0, BsW + 2048);
    __syncthreads();

    bf16x8 af[4], bf[4];
#pragma unroll
    for (int mt = 0; mt < 4; ++mt)
      af[mt] = *(const bf16x8*)&As[(wm + mt * 16 + l15) * 32 + g * 8];
#pragma unroll
    for (int nt = 0; nt < 4; ++nt)
      bf[nt] = *(const bf16x8*)&Bs[(wn + nt * 16 + l15) * 32 + g * 8];
#pragma unroll
    for (int mt = 0; mt < 4; ++mt)
#pragma unroll
      for (int nt = 0; nt < 4; ++nt)
        acc[mt][nt] = __builtin_amdgcn_mfma_f32_16x16x32_bf16(
            af[mt], bf[nt], acc[mt][nt], 0, 0, 0);
  }

  const int col0 = bn * 128 + wn;
  if (which < 2) {
    short* C = which == 0 ? C0 : C1;
#pragma unroll
    for (int nt = 0; nt < 4; ++nt) {
      const int col = col0 + nt * 16 + l15;
      const float bb = bias[col];
#pragma unroll
      for (int mt = 0; mt < 4; ++mt) {
        const int m0 = bm * 128 + wm + mt * 16 + g * 4;
#pragma unroll
        for (int r = 0; r < 4; ++r)
          C[(size_t)(m0 + r) * 1024 + col] = f2bf((acc[mt][nt][r] + bb) * scale);
      }
    }
  } else {
#pragma unroll
    for (int nt = 0; nt < 4; ++nt) {
      const int col = col0 + nt * 16 + l15;
      const int h = col >> 6, dh = col & 63;
      const float bb = bias[col];
#pragma unroll
      for (int mt = 0; mt < 4; ++mt) {
        const int m0 = bm * 128 + wm + mt * 16 + g * 4;   // 4-aligned, same b
        const int bb_ = m0 >> 11, s0 = m0 & 2047;
        bf16x4 o;
#pragma unroll
        for (int r = 0; r < 4; ++r) o[r] = f2bf(acc[mt][nt][r] + bb);
        *(bf16x4*)&Cv[(((size_t)bb_ * 16 + h) * 64 + dh) * 2048 + s0] = o;
      }
    }
  }
}

// ---------------- output projection GEMM with inline attention-partial merge.
// A[m][k] = (O0+O1)[m][k] / (l0+l1)[m][k>>6]; split-K x2, atomic fp32 epilogue.
// Each thread stages TWO A rows: m and m+64 (128-row tile).
__global__ __launch_bounds__(256) void gemm_out(
    const short* __restrict__ Op, const float* __restrict__ Lp,
    const short* __restrict__ W, const float* __restrict__ bias,
    float* __restrict__ C) {
  __shared__ short As[128 * 32];
  __shared__ short Bs[128 * 32];
  const int tid  = threadIdx.x;
  const int bm   = (int)blockIdx.x >> 3;
  const int bn   = (int)blockIdx.x & 7;
  const int kh   = blockIdx.y;             // 0/1: K half
  const int lane = tid & 63, wid = tid >> 6;
  const int g = lane >> 4, l15 = lane & 15;
  const int wm = (wid >> 1) * 64, wn = (wid & 1) * 64;

  const int m = bm * 128 + (tid >> 2);     // A rows m and m+64
  const short* Arow = Op + (size_t)m * 1024 + (tid & 3) * 8;
  const short* Wg = W + (size_t)(bn * 128 + (tid >> 2)) * 1024 + (tid & 3) * 8;
  short* AsT = As + tid * 8;               // row tid>>2, chunk tid&3
  short* BsW = Bs + wid * 512;

  f32x4 acc[4][4];
#pragma unroll
  for (int i = 0; i < 4; ++i)
#pragma unroll
    for (int j = 0; j < 4; ++j) acc[i][j] = (f32x4){0.f, 0.f, 0.f, 0.f};

  for (int k0 = kh * 512; k0 < kh * 512 + 512; k0 += 32) {
    __syncthreads();
    // A: manual staging with partial-merge (o0+o1)*inv, rows m and m+64
    const int h = k0 >> 6;
    const float inv0 = 1.0f / (Lp[m * 16 + h] + Lp[NL + m * 16 + h]);
    const float inv1 = 1.0f / (Lp[(m + 64) * 16 + h] + Lp[NL + (m + 64) * 16 + h]);
    bf16x8 o0a = *(const bf16x8*)(Arow + k0);
    bf16x8 o1a = *(const bf16x8*)(Arow + NE + k0);
    bf16x8 o0b = *(const bf16x8*)(Arow + (size_t)64 * 1024 + k0);
    bf16x8 o1b = *(const bf16x8*)(Arow + NE + (size_t)64 * 1024 + k0);
    bf16x8 a0, a1;
#pragma unroll
    for (int j = 0; j < 8; ++j) {
      a0[j] = f2bf((bf2f(o0a[j]) + bf2f(o1a[j])) * inv0);
      a1[j] = f2bf((bf2f(o0b[j]) + bf2f(o1b[j])) * inv1);
    }
    *(bf16x8*)AsT          = a0;
    *(bf16x8*)(AsT + 2048) = a1;
    // B: DMA staging
    cp16(Wg + k0,             BsW);
    cp16(Wg + 64 * 1024 + k0, BsW + 2048);
    __syncthreads();

    bf16x8 af[4], bf[4];
#pragma unroll
    for (int mt = 0; mt < 4; ++mt)
      af[mt] = *(const bf16x8*)&As[(wm + mt * 16 + l15) * 32 + g * 8];
#pragma unroll
    for (int nt = 0; nt < 4; ++nt)
      bf[nt] = *(const bf16x8*)&Bs[(wn + nt * 16 + l15) * 32 + g * 8];
#pragma unroll
    for (int mt = 0; mt < 4; ++mt)
#pragma unroll
      for (int nt = 0; nt < 4; ++nt)
        acc[mt][nt] = __builtin_amdgcn_mfma_f32_16x16x32_bf16(
            af[mt], bf[nt], acc[mt][nt], 0, 0, 0);
  }

  const int col0 = bn * 128 + wn;
#pragma unroll
  for (int nt = 0; nt < 4; ++nt) {
    const int col = col0 + nt * 16 + l15;
    const float bb = kh == 0 ? bias[col] : 0.f;
#pragma unroll
    for (int mt = 0; mt < 4; ++mt) {
      const int m0 = bm * 128 + wm + mt * 16 + g * 4;
#pragma unroll
      for (int r = 0; r < 4; ++r)
        unsafeAtomicAdd(&C[(size_t)(m0 + r) * 1024 + col], acc[mt][nt][r] + bb);
    }
  }
}

// ---------------- flash attention, static-max exp2 softmax, split-keys x2.
// Swizzled K/V LDS tiles (stride 64 shorts, chunk ^ (row&7)).
__global__ __launch_bounds__(256) void attn_kernel(
    const short* __restrict__ Q, const short* __restrict__ K,
    const short* __restrict__ Vg, short* __restrict__ Op, float* __restrict__ Lp) {
  __shared__ short Kt[64 * 64];     // [key][dh] swizzled
  __shared__ short Vt[64 * 64];     // [dh][key] swizzled
  __shared__ short Pt[4][32][72];   // per-wave [qrow][key], stride 72 (~2-way)

  const int tid  = threadIdx.x;
  const int qt   = (int)blockIdx.x & 15;          // 16 q-tiles
  const int bh   = ((int)blockIdx.x >> 4) & 31;   // 32 (b,h)
  const int half = (int)blockIdx.x >> 9;          // 0/1: key half
  const int b    = bh >> 4, h = bh & 15;
  const int lane = tid & 63, wid = tid >> 6;
  const int g = lane >> 4, l15 = lane & 15;

  const int q0 = qt * 128 + wid * 32;
  bf16x8 qf[2][2];
#pragma unroll
  for (int mt = 0; mt < 2; ++mt) {
    const size_t base = (size_t)(b * 2048 + q0 + mt * 16 + l15) * 1024 + h * 64;
    qf[mt][0] = *(const bf16x8*)(Q + base + g * 8);
    qf[mt][1] = *(const bf16x8*)(Q + base + 32 + g * 8);
  }

  f32x4 o_acc[2][4];
#pragma unroll
  for (int i = 0; i < 2; ++i)
#pragma unroll
    for (int j = 0; j < 4; ++j) o_acc[i][j] = (f32x4){0.f, 0.f, 0.f, 0.f};
  float l_i[2][4];
#pragma unroll
  for (int i = 0; i < 2; ++i)
#pragma unroll
    for (int r = 0; r < 4; ++r) l_i[i][r] = 0.f;

  const int srow = tid >> 2, sch = tid & 3;
  const short* Kbase = K + (size_t)(b * 2048) * 1024 + h * 64 + sch * 8;
  const short* Vbase = Vg + (size_t)((b * 16 + h) * 64 + srow) * 2048 + sch * 8;

  for (int kt = half * 16; kt < half * 16 + 16; ++kt) {
    __syncthreads();
    {
      const short* krow = Kbase + (size_t)(kt * 64 + srow) * 1024;
      *(bf16x8*)&Kt[sw(srow, sch)]     = *(const bf16x8*)(krow);
      *(bf16x8*)&Kt[sw(srow, sch + 4)] = *(const bf16x8*)(krow + 32);
      *(bf16x8*)&Vt[sw(srow, sch)]     = *(const bf16x8*)(Vbase + kt * 64);
      *(bf16x8*)&Vt[sw(srow, sch + 4)] = *(const bf16x8*)(Vbase + kt * 64 + 32);
    }
    __syncthreads();

    f32x4 sv[2][4];
#pragma unroll
    for (int nt = 0; nt < 4; ++nt) {
      const int kr = nt * 16 + l15;
      bf16x8 kf0 = *(const bf16x8*)&Kt[sw(kr, g)];
      bf16x8 kf1 = *(const bf16x8*)&Kt[sw(kr, g + 4)];
#pragma unroll
      for (int mt = 0; mt < 2; ++mt) {
        f32x4 z = (f32x4){0.f, 0.f, 0.f, 0.f};
        z = __builtin_amdgcn_mfma_f32_16x16x32_bf16(qf[mt][0], kf0, z, 0, 0, 0);
        z = __builtin_amdgcn_mfma_f32_16x16x32_bf16(qf[mt][1], kf1, z, 0, 0, 0);
        sv[mt][nt] = z;
      }
    }

#pragma unroll
    for (int mt = 0; mt < 2; ++mt)
#pragma unroll
      for (int r = 0; r < 4; ++r) {
        float p0 = EXP2(sv[mt][0][r]);
        float p1 = EXP2(sv[mt][1][r]);
        float p2 = EXP2(sv[mt][2][r]);
        float p3 = EXP2(sv[mt][3][r]);
        l_i[mt][r] += (p0 + p1) + (p2 + p3);
        const int pr = mt * 16 + g * 4 + r;
        Pt[wid][pr][l15]      = f2bf(p0);
        Pt[wid][pr][16 + l15] = f2bf(p1);
        Pt[wid][pr][32 + l15] = f2bf(p2);
        Pt[wid][pr][48 + l15] = f2bf(p3);
      }
    // no barrier: Pt slab is wave-private; per-wave DS ops execute in order

    bf16x8 pf[2][2];
#pragma unroll
    for (int mt = 0; mt < 2; ++mt) {
      pf[mt][0] = *(const bf16x8*)&Pt[wid][mt * 16 + l15][g * 8];
      pf[mt][1] = *(const bf16x8*)&Pt[wid][mt * 16 + l15][32 + g * 8];
    }
#pragma unroll
    for (int nt = 0; nt < 4; ++nt) {
      const int vr = nt * 16 + l15;
      bf16x8 vf0 = *(const bf16x8*)&Vt[sw(vr, g)];
      bf16x8 vf1 = *(const bf16x8*)&Vt[sw(vr, g + 4)];
#pragma unroll
      for (int mt = 0; mt < 2; ++mt) {
        o_acc[mt][nt] = __builtin_amdgcn_mfma_f32_16x16x32_bf16(
            pf[mt][0], vf0, o_acc[mt][nt], 0, 0, 0);
        o_acc[mt][nt] = __builtin_amdgcn_mfma_f32_16x16x32_bf16(
            pf[mt][1], vf1, o_acc[mt][nt], 0, 0, 0);
      }
    }
  }

  // epilogue: write unnormalized O (bf16) + per-row l (fp32) partials
#pragma unroll
  for (int mt = 0; mt < 2; ++mt)
#pragma unroll
    for (int r = 0; r < 4; ++r) {
      float l = l_i[mt][r];
#pragma unroll
      for (int off = 1; off < 16; off <<= 1) l += __shfl_xor(l, off, 64);
      const int row = q0 + mt * 16 + g * 4 + r;
      const size_t bs = (size_t)(b * 2048 + row);
      if (l15 == 0) Lp[half * NL + bs * 16 + h] = l;
      const size_t base = half * NE + bs * 1024 + h * 64;
#pragma unroll
      for (int nt = 0; nt < 4; ++nt)
        Op[base + nt * 16 + l15] = f2bf(o_acc[mt][nt][r]);
    }
}

extern "C" void kernel_launch(void* const* d_in, const int* in_sizes, int n_in,
                              void* d_out, int out_size, void* d_ws, size_t ws_size,
                              hipStream_t stream) {
  (void)in_sizes; (void)n_in; (void)ws_size;
  const float* q  = (const float*)d_in[0];
  const float* k  = (const float*)d_in[1];
  const float* v  = (const float*)d_in[2];
  const float* Wq = (const float*)d_in[3];
  const float* bq = (const float*)d_in[4];
  const float* Wk = (const float*)d_in[5];
  const float* bk = (const float*)d_in[6];
  const float* Wv = (const float*)d_in[7];
  const float* bv = (const float*)d_in[8];
  const float* Wo = (const float*)d_in[9];
  const float* bo = (const float*)d_in[10];
  float* out = (float*)d_out;

  short* qb  = (short*)d_ws;       // bf16 inputs
  short* kb  = qb + NE;
  short* vb  = kb + NE;
  short* Wqb = vb + NE;            // bf16 weights
  short* Wkb = Wqb + NW;
  short* Wvb = Wkb + NW;
  short* Wob = Wvb + NW;
  short* Qw  = Wob + NW;           // projected Q (pre-scaled)
  short* Kw  = Qw + NE;
  short* Vtg = Kw + NE;            // projected V [b,h,dh,s]
  // dead-region reuse after gemm_qkv:
  short* Op  = kb;                 // attn partial O, 2*NE bf16 (kb+vb region)
  float* Lp  = (float*)Wqb;        // attn partial l, 2*NL fp32 (512 KB)

  cvt_kernel<<<dim3(1024, 16), 256, 0, stream>>>(q, k, v, Wq, Wk, Wv, Wo,
                                                 qb, kb, vb, Wqb, Wkb, Wvb, Wob);
  gemm_qkv<<<dim3(256, 3), 256, 0, stream>>>(qb, kb, vb, Wqb, Wkb, Wvb,
                                             bq, bk, bv, Qw, Kw, Vtg);
  attn_kernel<<<1024, 256, 0, stream>>>(Qw, Kw, Vtg, Op, Lp);
  hipMemsetAsync(out, 0, (size_t)out_size * sizeof(float), stream);
  gemm_out<<<dim3(256, 2), 256, 0, stream>>>(Op, Lp, Wob, bo, out);
}

// Round 8
// 241.677 us; speedup vs baseline: 1.1695x; 1.1695x over previous
//
#include <hip/hip_runtime.h>
#include <hip/hip_bf16.h>

// MultiHeadAttention B=2,S=2048,D=1024,H=16,Dh=64. fp32 I/O, bf16 MFMA compute.
// R8: attn reverted to R5 staging (best measured), full-keys, +register
// prefetch of next K/V tile; GEMMs use 2x(BK=32) panels per barrier (halves
// barrier drains, keeps DMA-compatible bank-optimal layout); gemm_out 64x128
// tiles (512 blocks), no split-K/atomics/memset.

typedef short bf16x8 __attribute__((ext_vector_type(8)));
typedef short bf16x4 __attribute__((ext_vector_type(4)));
typedef float f32x4  __attribute__((ext_vector_type(4)));

constexpr size_t NE = (size_t)4096 * 1024;   // elems of [B*S, D]
constexpr size_t NW = (size_t)1024 * 1024;   // elems of [D, D]

#if __has_builtin(__builtin_amdgcn_exp2f)
#define EXP2(x) __builtin_amdgcn_exp2f(x)
#else
#define EXP2(x) exp2f(x)
#endif

__device__ __forceinline__ short f2bf(float f) {
  __hip_bfloat16 h = __float2bfloat16(f);
  return *reinterpret_cast<short*>(&h);
}

__device__ __forceinline__ void cp16(const short* g, short* l) {
  __builtin_amdgcn_global_load_lds(
      (const __attribute__((address_space(1))) void*)g,
      (__attribute__((address_space(3))) void*)l, 16, 0, 0);
}

// ---------------- fused fp32 -> bf16 conversion, 16 slices of 1M elems
__global__ __launch_bounds__(256) void cvt_kernel(
    const float* q, const float* k, const float* v,
    const float* Wq, const float* Wk, const float* Wv, const float* Wo,
    short* qb, short* kb, short* vb,
    short* Wqb, short* Wkb, short* Wvb, short* Wob) {
  const int y = blockIdx.y;
  const float* s; short* d;
  if (y < 12) {
    const int t = y >> 2;
    const size_t off = (size_t)(y & 3) << 20;
    s = (t == 0 ? q : (t == 1 ? k : v)) + off;
    d = (t == 0 ? qb : (t == 1 ? kb : vb)) + off;
  } else {
    s = (y == 12 ? Wq : (y == 13 ? Wk : (y == 14 ? Wv : Wo)));
    d = (y == 12 ? Wqb : (y == 13 ? Wkb : (y == 14 ? Wvb : Wob)));
  }
  size_t i = (size_t)blockIdx.x * 256 + threadIdx.x;
  float4 val = ((const float4*)s)[i];
  bf16x4 o;
  o[0] = f2bf(val.x); o[1] = f2bf(val.y); o[2] = f2bf(val.z); o[3] = f2bf(val.w);
  ((bf16x4*)d)[i] = o;
}

// ---------------- fused Q/K/V projection GEMM: C = (A @ W^T + b) * scale
// 128x128 tile, 2 x BK=32 panels per barrier round (16 rounds), DMA staging.
__global__ __launch_bounds__(256) void gemm_qkv(
    const short* __restrict__ A0, const short* __restrict__ A1, const short* __restrict__ A2,
    const short* __restrict__ W0, const short* __restrict__ W1, const short* __restrict__ W2,
    const float* __restrict__ b0, const float* __restrict__ b1, const float* __restrict__ b2,
    short* __restrict__ C0, short* __restrict__ C1, short* __restrict__ Cv) {
  __shared__ short As[2][128 * 32];
  __shared__ short Bs[2][128 * 32];
  const int which = blockIdx.y;
  const short* A    = which == 0 ? A0 : (which == 1 ? A1 : A2);
  const short* W    = which == 0 ? W0 : (which == 1 ? W1 : W2);
  const float* bias = which == 0 ? b0 : (which == 1 ? b1 : b2);
  const float scale = which == 0 ? 0.18033688011112042f : 1.0f;  // 0.125*log2e

  const int tid  = threadIdx.x;
  const int bm   = (int)blockIdx.x >> 3;
  const int bn   = (int)blockIdx.x & 7;
  const int lane = tid & 63, wid = tid >> 6;
  const int g = lane >> 4, l15 = lane & 15;
  const int wm = (wid >> 1) * 64, wn = (wid & 1) * 64;

  const short* Ag = A + (size_t)(bm * 128 + (tid >> 2)) * 1024 + (tid & 3) * 8;
  const short* Wg = W + (size_t)(bn * 128 + (tid >> 2)) * 1024 + (tid & 3) * 8;
  const int wofs = wid * 512;

  f32x4 acc[4][4];
#pragma unroll
  for (int i = 0; i < 4; ++i)
#pragma unroll
    for (int j = 0; j < 4; ++j) acc[i][j] = (f32x4){0.f, 0.f, 0.f, 0.f};

  for (int k0 = 0; k0 < 1024; k0 += 64) {
    __syncthreads();
#pragma unroll
    for (int p = 0; p < 2; ++p) {
      const int kk = k0 + p * 32;
      cp16(Ag + kk,             As[p] + wofs);
      cp16(Ag + 64 * 1024 + kk, As[p] + wofs + 2048);
      cp16(Wg + kk,             Bs[p] + wofs);
      cp16(Wg + 64 * 1024 + kk, Bs[p] + wofs + 2048);
    }
    __syncthreads();

#pragma unroll
    for (int p = 0; p < 2; ++p) {
      bf16x8 af[4], bf[4];
#pragma unroll
      for (int mt = 0; mt < 4; ++mt)
        af[mt] = *(const bf16x8*)&As[p][(wm + mt * 16 + l15) * 32 + g * 8];
#pragma unroll
      for (int nt = 0; nt < 4; ++nt)
        bf[nt] = *(const bf16x8*)&Bs[p][(wn + nt * 16 + l15) * 32 + g * 8];
#pragma unroll
      for (int mt = 0; mt < 4; ++mt)
#pragma unroll
        for (int nt = 0; nt < 4; ++nt)
          acc[mt][nt] = __builtin_amdgcn_mfma_f32_16x16x32_bf16(
              af[mt], bf[nt], acc[mt][nt], 0, 0, 0);
    }
  }

  const int col0 = bn * 128 + wn;
  if (which < 2) {
    short* C = which == 0 ? C0 : C1;
#pragma unroll
    for (int nt = 0; nt < 4; ++nt) {
      const int col = col0 + nt * 16 + l15;
      const float bb = bias[col];
#pragma unroll
      for (int mt = 0; mt < 4; ++mt) {
        const int m0 = bm * 128 + wm + mt * 16 + g * 4;
#pragma unroll
        for (int r = 0; r < 4; ++r)
          C[(size_t)(m0 + r) * 1024 + col] = f2bf((acc[mt][nt][r] + bb) * scale);
      }
    }
  } else {
    // V: write transposed per head [b,h,dh,s]
#pragma unroll
    for (int nt = 0; nt < 4; ++nt) {
      const int col = col0 + nt * 16 + l15;
      const int h = col >> 6, dh = col & 63;
      const float bb = bias[col];
#pragma unroll
      for (int mt = 0; mt < 4; ++mt) {
        const int m0 = bm * 128 + wm + mt * 16 + g * 4;   // 4-aligned, same b
        const int bb_ = m0 >> 11, s0 = m0 & 2047;
        bf16x4 o;
#pragma unroll
        for (int r = 0; r < 4; ++r) o[r] = f2bf(acc[mt][nt][r] + bb);
        *(bf16x4*)&Cv[(((size_t)bb_ * 16 + h) * 64 + dh) * 2048 + s0] = o;
      }
    }
  }
}

// ---------------- output projection: fp32 out = A(bf16) @ W^T + b
// 64x128 tile -> 512 blocks (2/CU); 2 x BK=32 panels per barrier round.
__global__ __launch_bounds__(256) void gemm_out(
    const short* __restrict__ A, const short* __restrict__ W,
    const float* __restrict__ bias, float* __restrict__ C) {
  __shared__ short As[2][64 * 32];
  __shared__ short Bs[2][128 * 32];
  const int tid  = threadIdx.x;
  const int bm   = (int)blockIdx.x >> 3;    // 64 M-tiles
  const int bn   = (int)blockIdx.x & 7;     // 8 N-tiles
  const int lane = tid & 63, wid = tid >> 6;
  const int g = lane >> 4, l15 = lane & 15;
  const int wm = (wid >> 1) * 32, wn = (wid & 1) * 64;

  const short* Ag = A + (size_t)(bm * 64 + (tid >> 2)) * 1024 + (tid & 3) * 8;
  const short* Wg = W + (size_t)(bn * 128 + (tid >> 2)) * 1024 + (tid & 3) * 8;
  const int wofs = wid * 512;

  f32x4 acc[2][4];
#pragma unroll
  for (int i = 0; i < 2; ++i)
#pragma unroll
    for (int j = 0; j < 4; ++j) acc[i][j] = (f32x4){0.f, 0.f, 0.f, 0.f};

  for (int k0 = 0; k0 < 1024; k0 += 64) {
    __syncthreads();
#pragma unroll
    for (int p = 0; p < 2; ++p) {
      const int kk = k0 + p * 32;
      cp16(Ag + kk,             As[p] + tid * 8 - tid * 8 + wofs);  // wave-uniform base
      cp16(Wg + kk,             Bs[p] + wofs);
      cp16(Wg + 64 * 1024 + kk, Bs[p] + wofs + 2048);
    }
    __syncthreads();

#pragma unroll
    for (int p = 0; p < 2; ++p) {
      bf16x8 af[2], bf[4];
#pragma unroll
      for (int mt = 0; mt < 2; ++mt)
        af[mt] = *(const bf16x8*)&As[p][(wm + mt * 16 + l15) * 32 + g * 8];
#pragma unroll
      for (int nt = 0; nt < 4; ++nt)
        bf[nt] = *(const bf16x8*)&Bs[p][(wn + nt * 16 + l15) * 32 + g * 8];
#pragma unroll
      for (int mt = 0; mt < 2; ++mt)
#pragma unroll
        for (int nt = 0; nt < 4; ++nt)
          acc[mt][nt] = __builtin_amdgcn_mfma_f32_16x16x32_bf16(
              af[mt], bf[nt], acc[mt][nt], 0, 0, 0);
    }
  }

  const int col0 = bn * 128 + wn;
#pragma unroll
  for (int nt = 0; nt < 4; ++nt) {
    const int col = col0 + nt * 16 + l15;
    const float bb = bias[col];
#pragma unroll
    for (int mt = 0; mt < 2; ++mt) {
      const int m0 = bm * 64 + wm + mt * 16 + g * 4;
#pragma unroll
      for (int r = 0; r < 4; ++r)
        C[(size_t)(m0 + r) * 1024 + col] = acc[mt][nt][r] + bb;
    }
  }
}

// ---------------- flash attention, static-max exp2 softmax, full keys.
// R5 staging layout (stride 72). Register prefetch of next K/V tile overlaps
// global latency with compute. Q-tile 128/wg; grid 512.
__global__ __launch_bounds__(256) void attn_kernel(
    const short* __restrict__ Q, const short* __restrict__ K,
    const short* __restrict__ Vg, short* __restrict__ O) {
  __shared__ short Kt[64][72];      // [key][dh]
  __shared__ short Vt[64][72];      // [dh][key]
  __shared__ short Pt[4][32][72];   // per-wave [qrow][key]

  const int tid  = threadIdx.x;
  const int qt   = (int)blockIdx.x & 15;    // 16 q-tiles
  const int bh   = (int)blockIdx.x >> 4;    // 32 (b,h)
  const int b    = bh >> 4, h = bh & 15;
  const int lane = tid & 63, wid = tid >> 6;
  const int g = lane >> 4, l15 = lane & 15;

  const int q0 = qt * 128 + wid * 32;
  bf16x8 qf[2][2];
#pragma unroll
  for (int mt = 0; mt < 2; ++mt) {
    const size_t base = (size_t)(b * 2048 + q0 + mt * 16 + l15) * 1024 + h * 64;
    qf[mt][0] = *(const bf16x8*)(Q + base + g * 8);
    qf[mt][1] = *(const bf16x8*)(Q + base + 32 + g * 8);
  }

  f32x4 o_acc[2][4];
#pragma unroll
  for (int i = 0; i < 2; ++i)
#pragma unroll
    for (int j = 0; j < 4; ++j) o_acc[i][j] = (f32x4){0.f, 0.f, 0.f, 0.f};
  float l_i[2][4];
#pragma unroll
  for (int i = 0; i < 2; ++i)
#pragma unroll
    for (int r = 0; r < 4; ++r) l_i[i][r] = 0.f;

  const int srow = tid >> 2, sch = tid & 3;
  const short* Kbase = K + (size_t)(b * 2048) * 1024 + h * 64 + sch * 8;
  const short* Vbase = Vg + (size_t)((b * 16 + h) * 64 + srow) * 2048 + sch * 8;

  // prefetch tile 0 into registers
  bf16x8 nk0, nk1, nv0, nv1;
  {
    const short* krow = Kbase + (size_t)srow * 1024;
    nk0 = *(const bf16x8*)(krow);
    nk1 = *(const bf16x8*)(krow + 32);
    nv0 = *(const bf16x8*)(Vbase);
    nv1 = *(const bf16x8*)(Vbase + 32);
  }

  for (int kt = 0; kt < 32; ++kt) {
    __syncthreads();   // previous tile's LDS reads done
    *(bf16x8*)&Kt[srow][sch * 8]      = nk0;
    *(bf16x8*)&Kt[srow][sch * 8 + 32] = nk1;
    *(bf16x8*)&Vt[srow][sch * 8]      = nv0;
    *(bf16x8*)&Vt[srow][sch * 8 + 32] = nv1;
    __syncthreads();

    // issue next tile's global loads now; they complete during compute
    if (kt < 31) {
      const short* krow = Kbase + (size_t)((kt + 1) * 64 + srow) * 1024;
      nk0 = *(const bf16x8*)(krow);
      nk1 = *(const bf16x8*)(krow + 32);
      nv0 = *(const bf16x8*)(Vbase + (kt + 1) * 64);
      nv1 = *(const bf16x8*)(Vbase + (kt + 1) * 64 + 32);
    }

    // S = Q K^T (exp2 domain): col=key(l15), row=q(g*4+r)
    f32x4 sv[2][4];
#pragma unroll
    for (int nt = 0; nt < 4; ++nt) {
      bf16x8 kf0 = *(const bf16x8*)&Kt[nt * 16 + l15][g * 8];
      bf16x8 kf1 = *(const bf16x8*)&Kt[nt * 16 + l15][32 + g * 8];
#pragma unroll
      for (int mt = 0; mt < 2; ++mt) {
        f32x4 z = (f32x4){0.f, 0.f, 0.f, 0.f};
        z = __builtin_amdgcn_mfma_f32_16x16x32_bf16(qf[mt][0], kf0, z, 0, 0, 0);
        z = __builtin_amdgcn_mfma_f32_16x16x32_bf16(qf[mt][1], kf1, z, 0, 0, 0);
        sv[mt][nt] = z;
      }
    }

    // static-max softmax: p = exp2(s), lane-local l accumulation, P -> LDS
#pragma unroll
    for (int mt = 0; mt < 2; ++mt)
#pragma unroll
      for (int r = 0; r < 4; ++r) {
        float p0 = EXP2(sv[mt][0][r]);
        float p1 = EXP2(sv[mt][1][r]);
        float p2 = EXP2(sv[mt][2][r]);
        float p3 = EXP2(sv[mt][3][r]);
        l_i[mt][r] += (p0 + p1) + (p2 + p3);
        const int pr = mt * 16 + g * 4 + r;
        Pt[wid][pr][l15]      = f2bf(p0);
        Pt[wid][pr][16 + l15] = f2bf(p1);
        Pt[wid][pr][32 + l15] = f2bf(p2);
        Pt[wid][pr][48 + l15] = f2bf(p3);
      }
    // no barrier: Pt slab is wave-private; per-wave DS ops execute in order

    bf16x8 pf[2][2];
#pragma unroll
    for (int mt = 0; mt < 2; ++mt) {
      pf[mt][0] = *(const bf16x8*)&Pt[wid][mt * 16 + l15][g * 8];
      pf[mt][1] = *(const bf16x8*)&Pt[wid][mt * 16 + l15][32 + g * 8];
    }
#pragma unroll
    for (int nt = 0; nt < 4; ++nt) {
      bf16x8 vf0 = *(const bf16x8*)&Vt[nt * 16 + l15][g * 8];
      bf16x8 vf1 = *(const bf16x8*)&Vt[nt * 16 + l15][32 + g * 8];
#pragma unroll
      for (int mt = 0; mt < 2; ++mt) {
        o_acc[mt][nt] = __builtin_amdgcn_mfma_f32_16x16x32_bf16(
            pf[mt][0], vf0, o_acc[mt][nt], 0, 0, 0);
        o_acc[mt][nt] = __builtin_amdgcn_mfma_f32_16x16x32_bf16(
            pf[mt][1], vf1, o_acc[mt][nt], 0, 0, 0);
      }
    }
  }

  // epilogue: reduce l across 16 lanes, normalize, store bf16
#pragma unroll
  for (int mt = 0; mt < 2; ++mt)
#pragma unroll
    for (int r = 0; r < 4; ++r) {
      float l = l_i[mt][r];
#pragma unroll
      for (int off = 1; off < 16; off <<= 1) l += __shfl_xor(l, off, 64);
      const float inv = 1.0f / l;
      const int row = q0 + mt * 16 + g * 4 + r;
      const size_t base = (size_t)(b * 2048 + row) * 1024 + h * 64;
#pragma unroll
      for (int nt = 0; nt < 4; ++nt)
        O[base + nt * 16 + l15] = f2bf(o_acc[mt][nt][r] * inv);
    }
}

extern "C" void kernel_launch(void* const* d_in, const int* in_sizes, int n_in,
                              void* d_out, int out_size, void* d_ws, size_t ws_size,
                              hipStream_t stream) {
  (void)in_sizes; (void)n_in; (void)out_size; (void)ws_size;
  const float* q  = (const float*)d_in[0];
  const float* k  = (const float*)d_in[1];
  const float* v  = (const float*)d_in[2];
  const float* Wq = (const float*)d_in[3];
  const float* bq = (const float*)d_in[4];
  const float* Wk = (const float*)d_in[5];
  const float* bk = (const float*)d_in[6];
  const float* Wv = (const float*)d_in[7];
  const float* bv = (const float*)d_in[8];
  const float* Wo = (const float*)d_in[9];
  const float* bo = (const float*)d_in[10];
  float* out = (float*)d_out;

  short* qb  = (short*)d_ws;       // bf16 inputs
  short* kb  = qb + NE;
  short* vb  = kb + NE;
  short* Wqb = vb + NE;            // bf16 weights
  short* Wkb = Wqb + NW;
  short* Wvb = Wkb + NW;
  short* Wob = Wvb + NW;
  short* Qw  = Wob + NW;           // projected Q (pre-scaled)
  short* Kw  = Qw + NE;
  short* Vtg = Kw + NE;            // projected V [b,h,dh,s]
  short* Ob  = qb;                 // attention out (qb dead after gemm_qkv)

  cvt_kernel<<<dim3(1024, 16), 256, 0, stream>>>(q, k, v, Wq, Wk, Wv, Wo,
                                                 qb, kb, vb, Wqb, Wkb, Wvb, Wob);
  gemm_qkv<<<dim3(256, 3), 256, 0, stream>>>(qb, kb, vb, Wqb, Wkb, Wvb,
                                             bq, bk, bv, Qw, Kw, Vtg);
  attn_kernel<<<512, 256, 0, stream>>>(Qw, Kw, Vtg, Ob);
  gemm_out<<<512, 256, 0, stream>>>(Ob, Wob, bo, out);
}